// Round 10
// baseline (28.078 us; speedup 1.0000x reference)
//
#include <hip/hip_runtime.h>
#include <math.h>

#define BB_ 512
#define NN_ 128
#define DD_ 64
#define NE_ 6
#define NB_ 4

// f32 workspace region (float offsets)
#define WS_PAIRE 0    // 144 floats
#define WS_E1    160  // 512 floats: per-molecule (vdW + atomic_e) partial
// ushort region at float offset 1024:
//   [0, 768*256)        stability bf16 table, row (n*6+t)*256 + o
//   [TDOFF_, +768*256)  druglikeness bf16 table
//   [W2OFF_ + which*32768, +32768) W2 bf16 (o*128+k)
#define U16BASE_ 1024
#define TDOFF_   (768 * 256)
#define W2OFF_   (1536 * 256)

typedef unsigned short u16x8 __attribute__((ext_vector_type(8)));

__device__ __forceinline__ ushort f2b(float f) {
  unsigned u = __float_as_uint(f);
  u += 0x7FFFu + ((u >> 16) & 1u);
  return (ushort)(u >> 16);
}
__device__ __forceinline__ float b2f(ushort h) {
  return __uint_as_float(((unsigned)h) << 16);
}

// ---------------------------------------------------------------------------
__device__ __forceinline__ float block_reduce256(float v, volatile float* red4,
                                                 int tid) {
#pragma unroll
  for (int off = 32; off > 0; off >>= 1) v += __shfl_down(v, off);
  __syncthreads();
  if ((tid & 63) == 0) red4[tid >> 6] = v;
  __syncthreads();
  return red4[0] + red4[1] + red4[2] + red4[3];
}

// ---------------------------------------------------------------------------
// k_a (launch 1, 1696 blocks): all work independent of the tables.
//   id<1536: c=id%3 -> 0: bf16 table build (m=id/3 in [0,512))
//                     1: x-write          (m=id/3)
//                     2: vdW+variance+linear, self-contained (m=id/3)
//   [1536,1680): pairE entries
//   [1680,1696): W2 bf16 conversion
// ---------------------------------------------------------------------------
__global__ __launch_bounds__(256, 4) void k_a(
    const float* __restrict__ emb, const float* __restrict__ ae_w,
    const float* __restrict__ ae_b, const float* __restrict__ ent_w,
    const float* __restrict__ ent_b, const float* __restrict__ bW,
    const float* __restrict__ sW1, const float* __restrict__ dW1,
    const float* __restrict__ sW2, const float* __restrict__ dW2,
    const int* __restrict__ atom_types, const float* __restrict__ pos,
    float* __restrict__ ws, float* __restrict__ out) {
  int id = blockIdx.x;
  int tid = threadIdx.x;
  ushort* U = (ushort*)(ws + U16BASE_);
  __shared__ float smem[1160];
  volatile float* red4 = smem + 1152;

  if (id < 1536) {
    int m = id / 3;
    int c = id - m * 3;
    if (c == 0) {
      // ---- bf16 layer1 table build: n=m>>2, which=(m>>1)&1, ohalf=m&1
      int n = m >> 2;
      int which = (m >> 1) & 1;
      int ohalf = m & 1;
      const float* W1 = which ? dW1 : sW1;
      ushort* T = U + (which ? TDOFF_ : 0);
      float* e_s = smem;          // 384
      float* part = smem + 384;   // [6][128]
      for (int i = tid; i < NE_ * DD_; i += 256) e_s[i] = emb[i];
      __syncthreads();
      int o_local = tid & 127;
      int dhalf = tid >> 7;
      int o = ohalf * 128 + o_local;
      float acc[NE_] = {0.f, 0.f, 0.f, 0.f, 0.f, 0.f};
      const float* Wp = W1 + ((size_t)(n * DD_ + dhalf * 32)) * 256 + o;
#pragma unroll 8
      for (int d = 0; d < 32; ++d) {
        float w = Wp[(size_t)d * 256];
#pragma unroll
        for (int t = 0; t < NE_; ++t)
          acc[t] += e_s[t * DD_ + dhalf * 32 + d] * w;
      }
      if (dhalf == 1) {
#pragma unroll
        for (int t = 0; t < NE_; ++t) part[t * 128 + o_local] = acc[t];
      }
      __syncthreads();
      if (dhalf == 0) {
#pragma unroll
        for (int t = 0; t < NE_; ++t)
          T[(n * NE_ + t) * 256 + o] = f2b(acc[t] + part[t * 128 + o_local]);
      }
    } else if (c == 1) {
      // ---- x-write
      float* e_s = smem;  // 384
      unsigned char* tyb = (unsigned char*)(smem + 384);
      for (int i = tid; i < NE_ * DD_; i += 256) e_s[i] = emb[i];
      if (tid < 32) {
        int4 t4 = ((const int4*)(atom_types + (size_t)m * NN_))[tid];
        uchar4 u4;
        u4.x = (unsigned char)t4.x;
        u4.y = (unsigned char)t4.y;
        u4.z = (unsigned char)t4.z;
        u4.w = (unsigned char)t4.w;
        ((uchar4*)tyb)[tid] = u4;
      }
      __syncthreads();
      float4* out4 = (float4*)(out + 2048 + (size_t)m * (NN_ * DD_));
#pragma unroll
      for (int u = 0; u < 8; ++u) {
        int li = tid + (u << 8);
        int n = li >> 4;
        int d0 = (li & 15) << 2;
        out4[li] = *(const float4*)&e_s[tyb[n] * DD_ + d0];
      }
    } else {
      // ---- vdW + variance + linear (self-contained)
      float4* p4 = (float4*)smem;  // 512 f
      float* aev = smem + 520;     // 6
      float* entv = smem + 528;    // 6
      float* redm = smem + 544;    // 32
      if (tid < 128) {
        const float* pm = pos + (size_t)m * NN_ * 3 + 3 * tid;
        p4[tid] = make_float4(pm[0], pm[1], pm[2], 0.f);
      } else if (tid < 224) {
        // 12 dot products: v=0..5 atomic_e per type, v=6..11 entropy per type
        int v = (tid - 128) >> 3;
        int l8 = tid & 7;
        int t = v - (v >= 6 ? 6 : 0);
        const float* wv = (v >= 6) ? ent_w : ae_w;
        const float* er = emb + t * DD_ + l8 * 8;
        const float* wr = wv + l8 * 8;
        float s = 0.f;
#pragma unroll
        for (int u = 0; u < 8; ++u) s += er[u] * wr[u];
#pragma unroll
        for (int off = 4; off > 0; off >>= 1) s += __shfl_down(s, off, 8);
        if (l8 == 0) {
          if (v < 6)
            aev[v] = s + ae_b[0];
          else
            entv[v - 6] = s + ent_b[0];
        }
      }
      __syncthreads();

      int i = tid >> 1;
      int half = tid & 1;
      float4 pi = p4[i];
      float vp = 0.f;
#pragma unroll 8
      for (int u = 0; u < 64; ++u) {
        int j = (half << 6) + u;
        float4 pj = p4[j];
        float dx = pi.x - pj.x;
        float dy = pi.y - pj.y;
        float dz = pi.z - pj.z;
        float d2 = dx * dx + dy * dy + dz * dz;
        if (j > i && d2 > 0.f) {
          float rc = __builtin_amdgcn_rcpf(d2);
          float r6 = rc * rc * rc;
          vp += 0.4f * (r6 * r6 - r6);
        }
      }

      float x = 0.f, y = 0.f, z = 0.f, sq = 0.f, ae = 0.f, en = 0.f;
      if (tid < 128) {
        float4 p = p4[tid];
        x = p.x;
        y = p.y;
        z = p.z;
        sq = x * x + y * y + z * z;
        int t = atom_types[(size_t)m * NN_ + tid];
        ae = aev[t];
        en = entv[t];
      }
      float vals[7] = {vp, x, y, z, sq, ae, en};
#pragma unroll
      for (int v = 0; v < 7; ++v) {
#pragma unroll
        for (int off = 32; off > 0; off >>= 1)
          vals[v] += __shfl_down(vals[v], off);
      }
      int wv2 = tid >> 6, ln = tid & 63;
      if (ln == 0) {
#pragma unroll
        for (int v = 0; v < 7; ++v) redm[wv2 * 8 + v] = vals[v];
      }
      __syncthreads();
      if (tid == 0) {
        float S[7];
#pragma unroll
        for (int v = 0; v < 7; ++v)
          S[v] = redm[v] + redm[8 + v] + redm[16 + v] + redm[24 + v];
        float var = (S[4] - (S[1] * S[1] + S[2] * S[2] + S[3] * S[3]) *
                                (1.f / NN_)) *
                    (1.f / (NN_ - 1));
        ws[WS_E1 + m] = S[0] + S[5];            // energy partial
        out[BB_ + m] = S[6] + logf(1.f + var);  // entropy, single writer
      }
    }
  } else if (id < 1680) {
    // ---- pairE entries
    int e = id - 1536;
    int k = e / 36;
    int rem = e - k * 36;
    int ti = rem / 6, tj = rem - (rem / 6) * 6;
    int d = tid & 63;
    int qd = tid >> 6;
    const float* Wrow = bW + ((size_t)k * DD_ + d) * DD_ + qd * 16;
    const float* xj = emb + tj * DD_ + qd * 16;
    float a = 0.f;
#pragma unroll
    for (int u = 0; u < 16; ++u) a += Wrow[u] * xj[u];
    float c = emb[ti * DD_ + d] * a;
    c = block_reduce256(c, red4, tid);
    if (tid == 0) ws[WS_PAIRE + e] = c;
  } else {
    // ---- W2 bf16 conversion
    int base = (id - 1680) * 4096 + tid;
#pragma unroll
    for (int u = 0; u < 16; ++u) {
      int e = base + u * 256;
      int head = e >> 15;
      int idx = e & 32767;
      const float* src = head ? dW2 : sW2;
      U[W2OFF_ + e] = f2b(src[idx]);
    }
  }
}

// ---------------------------------------------------------------------------
// k_b (launch 2, 1024 blocks): dependent classes.
//   even id: bonds (m=id>>1), finale out[m] = bonds + ws[E1+m]
//   odd id : MLP 2 molecules (mlpid=id>>1; which=mlpid&1; mbase=(mlpid>>1)*2)
// ---------------------------------------------------------------------------
__global__ __launch_bounds__(256, 4) void k_b(
    const int* __restrict__ atom_types, const int* __restrict__ bonds,
    const float* __restrict__ bb, const float* __restrict__ sb1,
    const float* __restrict__ sb2, const float* __restrict__ sW3,
    const float* __restrict__ sb3, const float* __restrict__ db1,
    const float* __restrict__ db2, const float* __restrict__ dW3,
    const float* __restrict__ db3, const float* __restrict__ ws,
    float* __restrict__ out) {
  int id = blockIdx.x;
  int tid = threadIdx.x;
  const ushort* U = (const ushort*)(ws + U16BASE_);
  __shared__ float smem[2632];
  volatile float* red4 = smem + 2624;

  if ((id & 1) == 0) {
    // ================= bonds =================
    int m = id >> 1;
    float* pE = smem;                                   // 144
    float* bbv = smem + 144;                            // 4
    unsigned char* tyb = (unsigned char*)(smem + 160);  // 128 B

    if (tid < 32) {
      int4 t4 = ((const int4*)(atom_types + (size_t)m * NN_))[tid];
      uchar4 u4;
      u4.x = (unsigned char)t4.x;
      u4.y = (unsigned char)t4.y;
      u4.z = (unsigned char)t4.z;
      u4.w = (unsigned char)t4.w;
      ((uchar4*)tyb)[tid] = u4;
    }
    if (tid >= 64 && tid < 208) pE[tid - 64] = ws[WS_PAIRE + tid - 64];
    if (tid >= 224 && tid < 228) bbv[tid - 224] = bb[tid - 224];
    __syncthreads();

    const int4* b4 = (const int4*)(bonds + (size_t)m * NN_ * NN_);
    float bp = 0.f;
#pragma unroll 4
    for (int it = 0; it < 16; ++it) {
      int li = tid + (it << 8);
      int i = li >> 5;
      int c = li & 31;
      if (c * 4 + 3 > i) {
        int4 v = b4[li];
        int j0 = c << 2;
        int ti6 = tyb[i] * 6;
        if (j0 + 0 > i && v.x > 0)
          bp += pE[(v.x - 1) * 36 + ti6 + tyb[j0 + 0]] + bbv[v.x - 1];
        if (j0 + 1 > i && v.y > 0)
          bp += pE[(v.y - 1) * 36 + ti6 + tyb[j0 + 1]] + bbv[v.y - 1];
        if (j0 + 2 > i && v.z > 0)
          bp += pE[(v.z - 1) * 36 + ti6 + tyb[j0 + 2]] + bbv[v.z - 1];
        if (j0 + 3 > i && v.w > 0)
          bp += pE[(v.w - 1) * 36 + ti6 + tyb[j0 + 3]] + bbv[v.w - 1];
      }
    }
    float e = block_reduce256(bp, red4, tid);
    if (tid == 0) out[m] = e + ws[WS_E1 + m];  // single writer, no atomics
  } else {
    // ================= MLP: 2 molecules =================
    int mlpid = id >> 1;
    int which = mlpid & 1;
    int mbase = (mlpid >> 1) * 2;
    float* part = smem;       // [2][4][256] = 2048
    float* scr = smem;        // [2][2][128] = 512 (after part dead)
    float* h2 = smem + 512;   // [2][128] = 256
    float* h1 = smem + 2048;  // [2][256] = 512
    unsigned char* tyb = (unsigned char*)(smem + 2560);  // 256 B

    tyb[tid] = (unsigned char)atom_types[(size_t)mbase * NN_ + tid];
    __syncthreads();

    // ---- layer 1 phase A: thread = (mi, quarter q, o-octet ot)
    {
      int mi = tid >> 7;
      int q = (tid >> 5) & 3;
      int ot = tid & 31;
      const ushort* Tb = U + (which ? TDOFF_ : 0) + ot * 8;
      const unsigned char* ty = tyb + mi * NN_;
      float a[8] = {0.f, 0.f, 0.f, 0.f, 0.f, 0.f, 0.f, 0.f};
      int nb = q * 32;
      for (int n0 = 0; n0 < 32; n0 += 8) {
        u16x8 v[8];
#pragma unroll
        for (int u = 0; u < 8; ++u) {
          int n = nb + n0 + u;
          v[u] = *(const u16x8*)(Tb + ((n * 6 + (int)ty[n]) << 8));
        }
#pragma unroll
        for (int u = 0; u < 8; ++u) {
#pragma unroll
          for (int j = 0; j < 8; ++j) a[j] += b2f(v[u][j]);
        }
      }
      float* pp = part + mi * 1024 + q * 256 + ot * 8;
#pragma unroll
      for (int j = 0; j < 8; ++j) pp[j] = a[j];
    }
    __syncthreads();
    // ---- phase B: combine quarters + bias + relu (512 outputs)
    {
#pragma unroll
      for (int li = tid; li < 512; li += 256) {
        int mm = li >> 8;
        int o = li & 255;
        float s = part[mm * 1024 + o] + part[mm * 1024 + 256 + o] +
                  part[mm * 1024 + 512 + o] + part[mm * 1024 + 768 + o];
        h1[li] = fmaxf(s + (which ? db1 : sb1)[o], 0.f);
      }
    }
    __syncthreads();

    // ---- layer 2: thread = (k, o-half kh); bf16 W2 regs reused over 2 mols
    {
      int k = tid & 127;
      int kh = tid >> 7;
      const ushort* Wp = U + W2OFF_ + which * 32768 + kh * 16384 + k;
      float acc[2] = {0.f, 0.f};
      for (int o0 = 0; o0 < 128; o0 += 16) {
        float wf[16];
#pragma unroll
        for (int u = 0; u < 16; ++u) wf[u] = b2f(Wp[(o0 + u) << 7]);
#pragma unroll
        for (int mm = 0; mm < 2; ++mm) {
          const float* hp = h1 + mm * 256 + kh * 128 + o0;
          float s = 0.f;
#pragma unroll
          for (int u = 0; u < 16; ++u) s += hp[u] * wf[u];
          acc[mm] += s;
        }
      }
      // part region is dead (phase B consumed it) -> scr
      scr[kh * 256 + 0 * 128 + k] = acc[0];
      scr[kh * 256 + 1 * 128 + k] = acc[1];
    }
    __syncthreads();
    if (tid < 128) {
      float b2v = (which ? db2 : sb2)[tid];
#pragma unroll
      for (int mm = 0; mm < 2; ++mm)
        h2[mm * 128 + tid] =
            fmaxf(b2v + scr[mm * 128 + tid] + scr[256 + mm * 128 + tid], 0.f);
    }
    __syncthreads();

    // ---- layer 3: 2 parallel 32-lane reductions
    {
      int mm = tid >> 5;
      int ln = tid & 31;
      if (mm < 2) {
        const float* W3 = which ? dW3 : sW3;
        float s = 0.f;
#pragma unroll
        for (int u = 0; u < 4; ++u) {
          int kk = ln + (u << 5);
          s += h2[mm * 128 + kk] * W3[kk];
        }
#pragma unroll
        for (int off = 16; off > 0; off >>= 1) s += __shfl_down(s, off, 32);
        if (ln == 0) {
          float b3 = (which ? db3 : sb3)[0];
          out[(2 + which) * BB_ + mbase + mm] = 1.f / (1.f + __expf(-(s + b3)));
        }
      }
    }
  }
}

// ---------------------------------------------------------------------------
extern "C" void kernel_launch(void* const* d_in, const int* in_sizes, int n_in,
                              void* d_out, int out_size, void* d_ws,
                              size_t ws_size, hipStream_t stream) {
  const int* atom_types = (const int*)d_in[0];
  const float* positions = (const float*)d_in[1];
  const int* bonds = (const int*)d_in[2];
  const float* emb = (const float*)d_in[3];
  const float* ae_w = (const float*)d_in[4];
  const float* ae_b = (const float*)d_in[5];
  const float* ent_w = (const float*)d_in[6];
  const float* ent_b = (const float*)d_in[7];
  const float* bW = (const float*)d_in[8];
  const float* bb = (const float*)d_in[9];
  const float* sW1 = (const float*)d_in[10];
  const float* sb1 = (const float*)d_in[11];
  const float* sW2 = (const float*)d_in[12];
  const float* sb2 = (const float*)d_in[13];
  const float* sW3 = (const float*)d_in[14];
  const float* sb3 = (const float*)d_in[15];
  const float* dW1 = (const float*)d_in[16];
  const float* db1 = (const float*)d_in[17];
  const float* dW2 = (const float*)d_in[18];
  const float* db2 = (const float*)d_in[19];
  const float* dW3 = (const float*)d_in[20];
  const float* db3 = (const float*)d_in[21];
  float* out = (float*)d_out;
  float* ws = (float*)d_ws;

  hipLaunchKernelGGL(k_a, dim3(1696), dim3(256), 0, stream, emb, ae_w, ae_b,
                     ent_w, ent_b, bW, sW1, dW1, sW2, dW2, atom_types,
                     positions, ws, out);
  hipLaunchKernelGGL(k_b, dim3(1024), dim3(256), 0, stream, atom_types, bonds,
                     bb, sb1, sb2, sW3, sb3, db1, db2, dW3, db3, ws, out);
}